// Round 8
// baseline (203.137 us; speedup 1.0000x reference)
//
#include <hip/hip_runtime.h>
#include <hip/hip_bf16.h>

typedef __attribute__((ext_vector_type(8))) short short8;
typedef __attribute__((ext_vector_type(4))) float floatx4;
typedef __attribute__((ext_vector_type(16))) float floatx16;

#define L_SEQ 2048
#define EMB   1024
#define HD    64
#define QSCALE 0.18033688011112042f   /* 0.125 * log2(e) */
#define FIXMAX2 11.541560327111707f   /* 8 * log2(e) */

__device__ __forceinline__ unsigned short f2bf(float f) {
    unsigned int u = __float_as_uint(f);
    u += 0x7fffu + ((u >> 16) & 1u);   // RNE
    return (unsigned short)(u >> 16);
}
__device__ __forceinline__ unsigned pkbf(float a, float b) {
    return (unsigned)f2bf(a) | ((unsigned)f2bf(b) << 16);
}
__device__ __forceinline__ unsigned pkbf2(float a, float b) {
    __hip_bfloat162 h = __float22bfloat162_rn(make_float2(a, b));
    unsigned u; __builtin_memcpy(&u, &h, 4); return u;
}
__device__ __forceinline__ void gld_lds16(const void* g, void* l) {
    __builtin_amdgcn_global_load_lds(
        (const __attribute__((address_space(1))) unsigned*)g,
        (__attribute__((address_space(3))) unsigned*)l, 16, 0, 0);
}
__device__ __forceinline__ float fexp2(float x) {
    return __builtin_amdgcn_exp2f(x);   // v_exp_f32 (2^x)
}

// ---------- Kernel 0: convert weights + activations fp32 -> bf16 ----------
__global__ __launch_bounds__(256) void convert_all(
    const float* __restrict__ q, const float* __restrict__ k,
    const float* __restrict__ v, const float* __restrict__ ipw,
    const float* __restrict__ opw,
    unsigned short* __restrict__ Abq, unsigned short* __restrict__ Abk,
    unsigned short* __restrict__ Abv, unsigned short* __restrict__ Wipb,
    unsigned short* __restrict__ Wopb)
{
    const int NA = 1048576, NIP = 786432;        // float4 units
    int idx = blockIdx.x * 256 + threadIdx.x;    // 0 .. 4194303
    const float* src; unsigned short* dst; int o;
    if (idx < NA)            { src = q;   dst = Abq;  o = idx; }
    else if (idx < 2 * NA)   { src = k;   dst = Abk;  o = idx - NA; }
    else if (idx < 3 * NA)   { src = v;   dst = Abv;  o = idx - 2 * NA; }
    else if (idx < 3 * NA + NIP) { src = ipw; dst = Wipb; o = idx - 3 * NA; }
    else                     { src = opw; dst = Wopb; o = idx - 3 * NA - NIP; }
    float4 f = ((const float4*)src)[o];
    ((uint2*)dst)[o] = make_uint2(pkbf(f.x, f.y), pkbf(f.z, f.w));
}

// ---------- Kernel 1: QKV projection + FUSED fragment repack ----------------
// RETILED this round: 128(M) x 64(N) tiles -> grid (32,48) = 1536 blocks
// (4 blocks/CU vs 3; acc halves to 32 VGPR). Each block covers ONE head's
// 64 columns, both batches in the row interleave.
// Qf chunk cq=(nn*64+qt32)*4+kk : lane l holds Q[nn][qt32*32+(l&31)][kk*16+(l>>5)*8 ..+7]
// Kf chunk ck=(nn*64+t32)*4+kk  : lane l holds K[nn][t32*32+(l&31)][kk*16+(l>>5)*8 ..+7]
// Vf chunk cv=nn*256+kk2*2+dt   : lane l holds V[nn][dt*32+(l&31)][key=kk2*16+(l>>5)*8 ..+7]
__global__ __launch_bounds__(256, 4) void qkv_gemm(
    const unsigned short* __restrict__ Abq, const unsigned short* __restrict__ Abk,
    const unsigned short* __restrict__ Abv, const unsigned short* __restrict__ Wb,
    const float* __restrict__ Bip,
    unsigned short* __restrict__ Qf, unsigned short* __restrict__ Kf,
    unsigned short* __restrict__ Vf)
{
    __shared__ unsigned short lds[12288];        // As 8192 + Bs 4096; epilogue reuses
    unsigned short* As = lds;
    unsigned short* Bs = lds + 8192;

    const int tid = threadIdx.x, lane = tid & 63, w = tid >> 6;
    const int wm = (w & 1) * 64, wn = (w >> 1) * 32;
    const int m0 = blockIdx.x * 128, n0 = blockIdx.y * 64;
    const int cn = lane & 15, g = lane >> 4;
    const int z = n0 >> 10;                      // by<16 -> Q, <32 -> K, else V
    const unsigned short* Ag = (z == 0) ? Abq : (z == 1) ? Abk : Abv;

    floatx4 acc[4][2];
    #pragma unroll
    for (int i = 0; i < 4; ++i)
        #pragma unroll
        for (int j = 0; j < 2; ++j) acc[i][j] = (floatx4){0.f, 0.f, 0.f, 0.f};

    for (int k0 = 0; k0 < EMB; k0 += 64) {
        __syncthreads();
        #pragma unroll
        for (int p = 0; p < 4; ++p) {
            int u0 = (p * 4 + w) * 64, u = u0 + lane, row = u >> 3, sl = u & 7;
            gld_lds16(Ag + (size_t)(m0 + row) * EMB + k0 + ((sl ^ (row & 7)) * 8), &As[u0 * 8]);
            if (p < 2)
                gld_lds16(Wb + (size_t)(n0 + row) * EMB + k0 + ((sl ^ (row & 7)) * 8), &Bs[u0 * 8]);
        }
        __syncthreads();
        #pragma unroll
        for (int kc = 0; kc < 2; ++kc) {
            short8 a4[4], b4[2];
            #pragma unroll
            for (int i = 0; i < 4; ++i)
                a4[i] = *(const short8*)&As[(wm + i * 16 + cn) * 64 + (((kc * 4 + g) ^ (cn & 7)) * 8)];
            #pragma unroll
            for (int j = 0; j < 2; ++j)
                b4[j] = *(const short8*)&Bs[(wn + j * 16 + cn) * 64 + (((kc * 4 + g) ^ (cn & 7)) * 8)];
            #pragma unroll
            for (int i = 0; i < 4; ++i)
                #pragma unroll
                for (int j = 0; j < 2; ++j)
                    acc[i][j] = __builtin_amdgcn_mfma_f32_16x16x32_bf16(a4[i], b4[j], acc[i][j], 0, 0, 0);
        }
    }

    const int c32l = lane & 31, hi5 = lane >> 5;
    const int b2 = w >> 1;

    if (z < 2) {
        // ---- Q or K: stage [rr(128)][cl(64)] stride 72, emit fragment chunks
        __syncthreads();                 // other waves done reading As/Bs
        #pragma unroll
        for (int j = 0; j < 2; ++j) {
            int cl = wn + j * 16 + cn;
            float bv = Bip[n0 + cl];
            #pragma unroll
            for (int i = 0; i < 4; ++i)
                #pragma unroll
                for (int r = 0; r < 4; ++r) {
                    int rr = wm + i * 16 + g * 4 + r;
                    float vv = acc[i][j][r] + bv;
                    lds[rr * 72 + cl] = f2bf(z == 0 ? vv * QSCALE : vv);
                }
        }
        __syncthreads();
        // wave w: batch b2 = w>>1, 32-row subtile t32l = w&1; 4 chunks (kk)
        const int h0 = (n0 & 1023) >> 6;
        const int t32l = w & 1;
        const int nn = b2 * 16 + h0;
        unsigned short* Dst = (z == 0) ? Qf : Kf;
        const int rr = (t32l * 32 + c32l) * 2 + b2;
        #pragma unroll
        for (int kk = 0; kk < 4; ++kk) {
            uint4 val = *(const uint4*)&lds[rr * 72 + kk * 16 + hi5 * 8];
            int ck = (nn * 64 + (m0 >> 6) + t32l) * 4 + kk;
            *(uint4*)(Dst + (size_t)ck * 512 + lane * 8) = val;
        }
    } else {
        // ---- V: LDS-transposed stage [col(64)][b*64+key] stride 136 ----
        __syncthreads();
        #pragma unroll
        for (int j = 0; j < 2; ++j) {
            int col_l = wn + j * 16 + cn;
            float bv = Bip[n0 + col_l];
            #pragma unroll
            for (int i = 0; i < 4; ++i) {
                int rrb = wm + i * 16 + g * 4;
                int l0 = rrb >> 1;
                float v0 = acc[i][j][0] + bv, v1 = acc[i][j][1] + bv;
                float v2 = acc[i][j][2] + bv, v3 = acc[i][j][3] + bv;
                *(unsigned*)&lds[col_l * 136 +      l0] = pkbf(v0, v2);
                *(unsigned*)&lds[col_l * 136 + 64 + l0] = pkbf(v1, v3);
            }
        }
        __syncthreads();
        // emit Vf chunks: wave w -> batch b2, kk2l pair (w&1)*2..+1, dt 0..1
        const int h0 = (n0 - 2048) >> 6;
        const int nn = b2 * 16 + h0;
        #pragma unroll
        for (int cc = 0; cc < 4; ++cc) {
            int kk2l = (w & 1) * 2 + (cc >> 1), dt = cc & 1;
            int col_l = dt * 32 + c32l;
            int keyl = kk2l * 16 + hi5 * 8;
            uint4 val = *(const uint4*)&lds[col_l * 136 + b2 * 64 + keyl];
            int cv = nn * 256 + ((m0 >> 5) + kk2l) * 2 + dt;
            *(uint4*)(Vf + (size_t)cv * 512 + lane * 8) = val;
        }
    }
}

// ---------- Kernel 2: flash attention, 32x32 MFMA, in-register softmax ------
// (frozen this round -- at its VALU+MFMA work-sum floor, ~71% combined busy)
__global__ __launch_bounds__(256, 2) void flash_attn_k(
    const unsigned short* __restrict__ Qf, const unsigned short* __restrict__ Kf,
    const unsigned short* __restrict__ Vf, unsigned short* __restrict__ Oh)
{
    // XCD-aware remap of 1024 blocks: XCD k -> heads [4k,4k+4) (~3MB L2 set).
    const int id = blockIdx.y * 32 + blockIdx.x;
    const int xcd = id & 7, slot = id >> 3;
    const int n = xcd * 4 + (slot & 3);
    const int q0 = (slot >> 2) * 64;

    __shared__ float Uf[64 * 67];                // 17152 B single-region combine buf

    const int tid = threadIdx.x, lane = tid & 63, w = tid >> 6;
    const int c32 = lane & 31, hi = lane >> 5;

    // Q fragments from Qf chunks: cq = (n*64 + q0/32 + qt)*4 + kk
    short8 qf[2][4];
    #pragma unroll
    for (int qt = 0; qt < 2; ++qt)
        #pragma unroll
        for (int kk = 0; kk < 4; ++kk)
            qf[qt][kk] = *(const short8*)(Qf + ((size_t)((n * 64 + (q0 >> 5) + qt) * 4 + kk)) * 512 + lane * 8);

    floatx16 acc_o[2][2];
    #pragma unroll
    for (int qt = 0; qt < 2; ++qt)
        #pragma unroll
        for (int dt = 0; dt < 2; ++dt)
            #pragma unroll
            for (int r = 0; r < 16; ++r) acc_o[qt][dt][r] = 0.f;
    float lsum0 = 0.f, lsum1 = 0.f;

    const unsigned short* kbase = Kf + ((size_t)n * 256 + w * 64) * 512 + lane * 8;
    const unsigned short* vbase = Vf + ((size_t)n * 256 + w * 64) * 512 + lane * 8;

#define FLOAD(KF, VF, T) do {                                               \
    const unsigned short* _kp = kbase + (size_t)(T) * 2048;                 \
    const unsigned short* _vp = vbase + (size_t)(T) * 2048;                 \
    _Pragma("unroll")                                                       \
    for (int kk = 0; kk < 4; ++kk)                                          \
        KF[kk] = *(const short8*)(_kp + kk * 512);                          \
    _Pragma("unroll")                                                       \
    for (int kc = 0; kc < 2; ++kc)                                          \
        _Pragma("unroll")                                                   \
        for (int dt = 0; dt < 2; ++dt)                                      \
            VF[kc][dt] = *(const short8*)(_vp + (kc * 2 + dt) * 512);       \
} while (0)

#define FCOMP(KF, VF) do {                                                  \
    floatx16 s_[2];                                                         \
    _Pragma("unroll")                                                       \
    for (int qt = 0; qt < 2; ++qt) {                                        \
        _Pragma("unroll")                                                   \
        for (int r = 0; r < 16; ++r) s_[qt][r] = -FIXMAX2;                  \
        __builtin_amdgcn_s_setprio(1);                                      \
        _Pragma("unroll")                                                   \
        for (int kk = 0; kk < 4; ++kk)                                      \
            s_[qt] = __builtin_amdgcn_mfma_f32_32x32x16_bf16(KF[kk], qf[qt][kk], s_[qt], 0, 0, 0); \
        __builtin_amdgcn_s_setprio(0);                                      \
    }                                                                       \
    _Pragma("unroll")                                                       \
    for (int qt = 0; qt < 2; ++qt) {                                        \
        float p_[16];                                                       \
        _Pragma("unroll")                                                   \
        for (int r = 0; r < 16; ++r) p_[r] = fexp2(s_[qt][r]);              \
        float ls_ = ((p_[0] + p_[1]) + (p_[2] + p_[3])) + ((p_[4] + p_[5]) + (p_[6] + p_[7])) \
                  + ((p_[8] + p_[9]) + (p_[10] + p_[11])) + ((p_[12] + p_[13]) + (p_[14] + p_[15])); \
        if (qt == 0) lsum0 += ls_; else lsum1 += ls_;                       \
        short8 pa_[2];                                                      \
        _Pragma("unroll")                                                   \
        for (int kc = 0; kc < 2; ++kc) {                                    \
            unsigned A_ = pkbf2(p_[kc * 8 + 0], p_[kc * 8 + 1]);            \
            unsigned B_ = pkbf2(p_[kc * 8 + 2], p_[kc * 8 + 3]);            \
            unsigned C_ = pkbf2(p_[kc * 8 + 4], p_[kc * 8 + 5]);            \
            unsigned D_ = pkbf2(p_[kc * 8 + 6], p_[kc * 8 + 7]);            \
            asm("v_permlane32_swap_b32 %0, %1" : "+v"(A_), "+v"(C_));       \
            asm("v_permlane32_swap_b32 %0, %1" : "+v"(B_), "+v"(D_));       \
            union { unsigned u[4]; short8 v; } cv_;                         \
            cv_.u[0] = A_; cv_.u[1] = B_; cv_.u[2] = C_; cv_.u[3] = D_;     \
            pa_[kc] = cv_.v;                                                \
        }                                                                   \
        __builtin_amdgcn_s_setprio(1);                                      \
        _Pragma("unroll")                                                   \
        for (int kc = 0; kc < 2; ++kc)                                      \
            _Pragma("unroll")                                               \
            for (int dt = 0; dt < 2; ++dt)                                  \
                acc_o[qt][dt] = __builtin_amdgcn_mfma_f32_32x32x16_bf16(pa_[kc], VF[kc][dt], acc_o[qt][dt], 0, 0, 0); \
        __builtin_amdgcn_s_setprio(0);                                      \
    }                                                                       \
} while (0)

    short8 kfA[4], vfA[2][2], kfB[4], vfB[2][2];
    FLOAD(kfA, vfA, 0);
    for (int t = 0; t < 16; t += 2) {
        FLOAD(kfB, vfB, t + 1);          // issue t+1 loads before computing t
        FCOMP(kfA, vfA);
        if (t + 2 < 16) FLOAD(kfA, vfA, t + 2);
        FCOMP(kfB, vfB);
    }
#undef FLOAD
#undef FCOMP

    // fold hi-halves of lsum: column totals on all lanes
    {
        float a0 = lsum0, b0 = lsum0;
        asm("v_permlane32_swap_b32 %0, %1" : "+v"(a0), "+v"(b0));
        lsum0 = a0 + b0;
        float a1 = lsum1, b1 = lsum1;
        asm("v_permlane32_swap_b32 %0, %1" : "+v"(a1), "+v"(b1));
        lsum1 = a1 + b1;
    }

    // ---- cross-wave combine: serial chain w3->w2->w1->w0 (exact sums) ----
#define BLOB_STORE() do {                                                  \
    _Pragma("unroll")                                                      \
    for (int qt = 0; qt < 2; ++qt)                                         \
        _Pragma("unroll")                                                  \
        for (int dt = 0; dt < 2; ++dt)                                     \
            _Pragma("unroll")                                              \
            for (int r = 0; r < 16; ++r)                                   \
                Uf[ub + (qt * 2 + dt) * 16 + r] = acc_o[qt][dt][r];        \
    Uf[ub + 64] = lsum0; Uf[ub + 65] = lsum1;                              \
} while (0)
#define BLOB_ADD() do {                                                    \
    _Pragma("unroll")                                                      \
    for (int qt = 0; qt < 2; ++qt)                                         \
        _Pragma("unroll")                                                  \
        for (int dt = 0; dt < 2; ++dt)                                     \
            _Pragma("unroll")                                              \
            for (int r = 0; r < 16; ++r)                                   \
                acc_o[qt][dt][r] += Uf[ub + (qt * 2 + dt) * 16 + r];       \
    lsum0 += Uf[ub + 64]; lsum1 += Uf[ub + 65];                            \
} while (0)

    const int ub = lane * 67;
    __syncthreads();
    if (w == 3) BLOB_STORE();
    __syncthreads();
    if (w == 2) { BLOB_ADD(); BLOB_STORE(); }
    __syncthreads();
    if (w == 1) { BLOB_ADD(); BLOB_STORE(); }
    __syncthreads();
    if (w == 0) {
        BLOB_ADD();
        // epilogue: per-column inverses live at lane=q; broadcast per-row via bpermute
        float inv0 = 1.0f / lsum0, inv1 = 1.0f / lsum1;
        const int hib = hi * 16;
        const int bb = n >> 4, h = n & 15;
        #pragma unroll
        for (int qt = 0; qt < 2; ++qt) {
            float invq = qt ? inv1 : inv0;
            #pragma unroll
            for (int r = 0; r < 16; ++r) {
                int idx = ((r & 3) + 8 * (r >> 2)) * 4 + hib;
                float invr = __int_as_float(__builtin_amdgcn_ds_bpermute(idx, __float_as_int(invq)));
                int q = q0 + qt * 32 + (r & 3) + 8 * (r >> 2) + hi * 4;
                #pragma unroll
                for (int dt = 0; dt < 2; ++dt) {
                    int e = h * 64 + dt * 32 + c32;
                    Oh[((size_t)q * 2 + bb) * EMB + e] = f2bf(acc_o[qt][dt][r] * invr);
                }
            }
        }
    }
#undef BLOB_STORE
#undef BLOB_ADD
}

// ---------- Kernel 3: output projection (all-bf16), 64x64 tiles -------------
// RETILED this round: grid (64,16) = 1024 blocks = 4 blocks/CU (vs 2),
// acc 16 VGPR -> ~16 waves/CU. XCD swizzle: XCD k owns M-rows [k*512,+512)
// (Oh slice 1 MB) + full Wob (2 MB) -> 3 MB L2-resident per XCD.
__global__ __launch_bounds__(256, 4) void out_gemm(
    const unsigned short* __restrict__ Oh, const unsigned short* __restrict__ Wob,
    const float* __restrict__ bo, float* __restrict__ out)
{
    __shared__ unsigned short As[64 * 64];
    __shared__ unsigned short Bs[64 * 64];

    const int tid = threadIdx.x, lane = tid & 63, w = tid >> 6;
    const int wm = (w & 1) * 32, wn = (w >> 1) * 32;
    const int id = blockIdx.y * 64 + blockIdx.x;
    const int xcd = id & 7, slot = id >> 3;
    const int m0 = (xcd * 8 + (slot & 7)) * 64;
    const int n0 = (slot >> 3) * 64;
    const int cn = lane & 15, g = lane >> 4;

    floatx4 acc[2][2];
    #pragma unroll
    for (int i = 0; i < 2; ++i)
        #pragma unroll
        for (int j = 0; j < 2; ++j) acc[i][j] = (floatx4){0.f, 0.f, 0.f, 0.f};

    for (int k0 = 0; k0 < EMB; k0 += 64) {
        __syncthreads();
        #pragma unroll
        for (int p = 0; p < 2; ++p) {
            int u0 = (p * 4 + w) * 64, u = u0 + lane, row = u >> 3, sl = u & 7;
            gld_lds16(Oh  + (size_t)(m0 + row) * EMB + k0 + ((sl ^ (row & 7)) * 8), &As[u0 * 8]);
            gld_lds16(Wob + (size_t)(n0 + row) * EMB + k0 + ((sl ^ (row & 7)) * 8), &Bs[u0 * 8]);
        }
        __syncthreads();
        #pragma unroll
        for (int kc = 0; kc < 2; ++kc) {
            short8 a4[2], b4[2];
            #pragma unroll
            for (int i = 0; i < 2; ++i)
                a4[i] = *(const short8*)&As[(wm + i * 16 + cn) * 64 + (((kc * 4 + g) ^ (cn & 7)) * 8)];
            #pragma unroll
            for (int j = 0; j < 2; ++j)
                b4[j] = *(const short8*)&Bs[(wn + j * 16 + cn) * 64 + (((kc * 4 + g) ^ (cn & 7)) * 8)];
            #pragma unroll
            for (int i = 0; i < 2; ++i)
                #pragma unroll
                for (int j = 0; j < 2; ++j)
                    acc[i][j] = __builtin_amdgcn_mfma_f32_16x16x32_bf16(a4[i], b4[j], acc[i][j], 0, 0, 0);
        }
    }

    #pragma unroll
    for (int j = 0; j < 2; ++j) {
        int col = n0 + wn + j * 16 + cn;
        float bv = bo[col];
        #pragma unroll
        for (int i = 0; i < 2; ++i)
            #pragma unroll
            for (int r = 0; r < 4; ++r)
                out[(size_t)(m0 + wm + i * 16 + g * 4 + r) * EMB + col] = acc[i][j][r] + bv;
    }
}

extern "C" void kernel_launch(void* const* d_in, const int* in_sizes, int n_in,
                              void* d_out, int out_size, void* d_ws, size_t ws_size,
                              hipStream_t stream) {
    const float* q   = (const float*)d_in[0];
    const float* k   = (const float*)d_in[1];
    const float* v   = (const float*)d_in[2];
    const float* ipw = (const float*)d_in[3];
    const float* ipb = (const float*)d_in[4];
    const float* opw = (const float*)d_in[5];
    const float* opb = (const float*)d_in[6];
    float* out = (float*)d_out;

    const size_t HE = (size_t)32 * L_SEQ * HD;           // 4,194,304 shorts
    unsigned short* Qf   = (unsigned short*)d_ws;        // 8 MB (fragment chunks)
    unsigned short* Kf   = Qf + HE;                      // 8 MB (fragment chunks)
    unsigned short* Vf   = Kf + HE;                      // 8 MB (fragment chunks)
    unsigned short* Wipb = Vf + HE;                      // 6 MB
    unsigned short* Wopb = Wipb + (size_t)3 * EMB * EMB; // 2 MB
    unsigned short* Abq  = Wopb + (size_t)EMB * EMB;     // 8 MB
    unsigned short* Abk  = Abq + HE;                     // 8 MB
    unsigned short* Abv  = Abk + HE;                     // 8 MB  (total 56 MB)
    unsigned short* Oh   = Abq;                          // dead after qkv_gemm

    convert_all<<<dim3(16384), 256, 0, stream>>>(q, k, v, ipw, opw, Abq, Abk, Abv, Wipb, Wopb);
    qkv_gemm<<<dim3(32, 48), 256, 0, stream>>>(Abq, Abk, Abv, Wipb, ipb, Qf, Kf, Vf);
    flash_attn_k<<<dim3(32, 32), 256, 0, stream>>>(Qf, Kf, Vf, Oh);
    out_gemm<<<dim3(64, 16), 256, 0, stream>>>(Oh, Wopb, opb, out);
}